// Round 3
// baseline (473.071 us; speedup 1.0000x reference)
//
#include <hip/hip_runtime.h>

constexpr int K_CODES = 512;
constexpr int D_DIM   = 64;
constexpr int HW      = 4096;               // 64*64
constexpr int BATCH   = 32;
constexpr int N_ROWS  = BATCH * HW;         // 131072
constexpr int HALF    = BATCH * D_DIM * HW; // elements per output tensor
constexpr int RPB     = 64;                 // rows per block (one per lane)
constexpr int KPW     = 128;                // codes per wave (512 / 4 waves)

// ee[k] = |e_k|^2: sequential d, separate mul/add rounding (matches f32 reference)
__global__ void ee_precompute(const float* __restrict__ emb, float* __restrict__ ee) {
#pragma clang fp contract(off)
    int k = blockIdx.x * blockDim.x + threadIdx.x;
    if (k < K_CODES) {
        const float* w = emb + k * D_DIM;
        float acc = 0.f;
        for (int d = 0; d < D_DIM; ++d) { float q = w[d] * w[d]; acc = acc + q; }
        ee[k] = acc;
    }
}

// Block: 256 threads = 4 waves over 64 rows. Lane <-> row, wave <-> code range
// (keeps codebook reads wave-uniform -> scalar-load path).
// Bit-exact reference emulation:
//   dist[n,k] = fl( fl(zz_n - fl(2*dot_nk)) + ee_k ),
//   zz sequential separate-rounded, dot sequential fma chain,
//   argmin = first occurrence of min (strict <, ascending k).
__global__ __launch_bounds__(256, 4) void vq_nearest(const float* __restrict__ zin,
                                                     const float* __restrict__ emb,
                                                     const float* __restrict__ ee,
                                                     float* __restrict__ out) {
#pragma clang fp contract(off)
    __shared__ float s_ee[K_CODES];
    __shared__ float s_best[4][RPB];
    __shared__ int   s_bidx[4][RPB];

    const int tid  = threadIdx.x;
    const int wave = tid >> 6;
    const int lane = tid & 63;

    for (int k = tid; k < K_CODES; k += 256) s_ee[k] = ee[k];
    __syncthreads();

    const int row = blockIdx.x * RPB + lane;
    const int b   = row >> 12;
    const int p   = row & (HW - 1);
    const float* zp = zin + (size_t)b * (D_DIM * HW) + p;

    // z row resident in VGPRs (launch_bounds cap 128 leaves room)
    float zr[D_DIM];
#pragma unroll
    for (int d = 0; d < D_DIM; ++d) zr[d] = zp[(size_t)d * HW];

    // zz: strict sequential sum of squares, separate rounding
    float zz = 0.f;
#pragma unroll
    for (int d = 0; d < D_DIM; ++d) { float q = zr[d] * zr[d]; zz = zz + q; }

    const int kbase = wave * KPW;
    float best = 3.4e38f;
    int   bi   = kbase;

    for (int k0 = 0; k0 < KPW; k0 += 8) {
        const float* w = emb + (size_t)(kbase + k0) * D_DIM;  // wave-uniform
        float dot[8];
#pragma unroll
        for (int j = 0; j < 8; ++j) dot[j] = 0.f;
#pragma unroll
        for (int d = 0; d < D_DIM; ++d) {
            const float z = zr[d];
#pragma unroll
            for (int j = 0; j < 8; ++j)
                dot[j] = __builtin_fmaf(w[j * D_DIM + d], z, dot[j]);
        }
#pragma unroll
        for (int j = 0; j < 8; ++j) {
            const float m    = 2.0f * dot[j];       // exact
            const float s    = zz - m;              // one rounding
            const float dist = s + s_ee[kbase + k0 + j];  // one rounding
            if (dist < best) { best = dist; bi = kbase + k0 + j; }
        }
    }

    s_best[wave][lane] = best;
    s_bidx[wave][lane] = bi;
    __syncthreads();

    // cross-wave argmin for this lane's row; wave order ascending in k, so
    // strict < preserves first-occurrence (lower-index) semantics exactly
    float b0 = s_best[0][lane];
    int   i0 = s_bidx[0][lane];
#pragma unroll
    for (int w2 = 1; w2 < 4; ++w2) {
        const float bw = s_best[w2][lane];
        const int   iw = s_bidx[w2][lane];
        if (bw < b0) { b0 = bw; i0 = iw; }
    }

    // gather + write both outputs; wave w covers d in [16w, 16w+16)
    const float* wb = emb + (size_t)i0 * D_DIM;
    float* o1 = out + (size_t)b * (D_DIM * HW) + p;
    float* o2 = o1 + HALF;
#pragma unroll
    for (int dd = 0; dd < 16; ++dd) {
        const int d = wave * 16 + dd;
        const float v = wb[d];
        o1[(size_t)d * HW] = v;
        o2[(size_t)d * HW] = v;
    }
}

extern "C" void kernel_launch(void* const* d_in, const int* in_sizes, int n_in,
                              void* d_out, int out_size, void* d_ws, size_t ws_size,
                              hipStream_t stream) {
    const float* z   = (const float*)d_in[0];
    const float* emb = (const float*)d_in[1];
    float* ee  = (float*)d_ws;
    float* out = (float*)d_out;
    hipLaunchKernelGGL(ee_precompute, dim3(2), dim3(256), 0, stream, emb, ee);
    hipLaunchKernelGGL(vq_nearest, dim3(N_ROWS / RPB), dim3(256), 0, stream,
                       z, emb, ee, out);
}

// Round 4
// 153.259 us; speedup vs baseline: 3.0867x; 3.0867x over previous
//
#include <hip/hip_runtime.h>

constexpr int K_CODES = 512;
constexpr int D_DIM   = 64;
constexpr int HW      = 4096;               // 64*64
constexpr int BATCH   = 32;
constexpr int N_ROWS  = BATCH * HW;         // 131072
constexpr int HALF    = BATCH * D_DIM * HW; // elements per output tensor
constexpr int RPB     = 64;                 // rows per block (one per lane)
constexpr int KPW     = 128;                // codes per wave (512 / 4 waves)

// ee[k] = |e_k|^2: sequential d, separate mul/add rounding (matches f32 reference)
__global__ void ee_precompute(const float* __restrict__ emb, float* __restrict__ ee) {
#pragma clang fp contract(off)
    int k = blockIdx.x * blockDim.x + threadIdx.x;
    if (k < K_CODES) {
        const float* w = emb + k * D_DIM;
        float acc = 0.f;
        for (int d = 0; d < D_DIM; ++d) { float q = w[d] * w[d]; acc = acc + q; }
        ee[k] = acc;
    }
}

// 256 threads = 4 waves over 64 rows; lane <-> row, wave <-> 128-code range.
// kbase forced into SGPR via readfirstlane so codebook/ee reads take the
// scalar-load (SMEM) path. zr[] pinned to VGPRs via asm so the k-loop never
// re-touches memory for z.
// Bit-exact f32 reference emulation (validated rounds 2-3, absmax 0.0):
//   dist = fl( fl(zz - fl(2*dot)) + ee ), zz sequential separate-rounded,
//   dot sequential fma chain, argmin first-occurrence (strict <, ascending k).
__global__ __launch_bounds__(256, 4) void vq_nearest(const float* __restrict__ zin,
                                                     const float* __restrict__ emb,
                                                     const float* __restrict__ ee,
                                                     float* __restrict__ out) {
#pragma clang fp contract(off)
    __shared__ float s_best[4][RPB];
    __shared__ int   s_bidx[4][RPB];

    const int tid  = threadIdx.x;
    const int wave = tid >> 6;
    const int lane = tid & 63;

    const int row = blockIdx.x * RPB + lane;
    const int b   = row >> 12;
    const int p   = row & (HW - 1);
    const float* zp = zin + (size_t)b * (D_DIM * HW) + p;

    // z row -> VGPRs, pinned so the compiler cannot sink/remat the loads
    float zr[D_DIM];
#pragma unroll
    for (int d = 0; d < D_DIM; ++d) zr[d] = zp[(size_t)d * HW];
#pragma unroll
    for (int d = 0; d < D_DIM; ++d) asm volatile("" : "+v"(zr[d]));

    // zz: strict sequential sum of squares, separate rounding
    float zz = 0.f;
#pragma unroll
    for (int d = 0; d < D_DIM; ++d) { float q = zr[d] * zr[d]; zz = zz + q; }

    // wave-uniform code range, forced into an SGPR
    const int kbase = __builtin_amdgcn_readfirstlane(wave) * KPW;
    const float* wbase  = emb + (size_t)kbase * D_DIM;  // uniform -> s_load
    const float* eebase = ee + kbase;                   // uniform -> s_load

    float best = 3.4e38f;
    int   bi   = kbase;

    for (int k0 = 0; k0 < KPW; k0 += 8) {
        const float* w = wbase + (size_t)k0 * D_DIM;
        float dot[8];
#pragma unroll
        for (int j = 0; j < 8; ++j) dot[j] = 0.f;
#pragma unroll
        for (int d = 0; d < D_DIM; ++d) {
            const float z = zr[d];
#pragma unroll
            for (int j = 0; j < 8; ++j)
                dot[j] = __builtin_fmaf(w[j * D_DIM + d], z, dot[j]);
        }
#pragma unroll
        for (int j = 0; j < 8; ++j) {
            const float m    = 2.0f * dot[j];        // exact
            const float s    = zz - m;               // one rounding
            const float dist = s + eebase[k0 + j];   // one rounding
            if (dist < best) { best = dist; bi = kbase + k0 + j; }
        }
    }

    s_best[wave][lane] = best;
    s_bidx[wave][lane] = bi;
    __syncthreads();

    // cross-wave argmin; wave order ascending in k, strict < keeps
    // first-occurrence semantics exact
    float b0 = s_best[0][lane];
    int   i0 = s_bidx[0][lane];
#pragma unroll
    for (int w2 = 1; w2 < 4; ++w2) {
        const float bw = s_best[w2][lane];
        if (bw < b0) { b0 = bw; i0 = s_bidx[w2][lane]; }
    }

    // gather + write both outputs; wave w covers d in [16w, 16w+16)
    const float* wb = emb + (size_t)i0 * D_DIM;
    float* o1 = out + (size_t)b * (D_DIM * HW) + p;
    float* o2 = o1 + HALF;
#pragma unroll
    for (int dd = 0; dd < 16; ++dd) {
        const int d = wave * 16 + dd;
        const float v = wb[d];
        o1[(size_t)d * HW] = v;
        o2[(size_t)d * HW] = v;
    }
}

extern "C" void kernel_launch(void* const* d_in, const int* in_sizes, int n_in,
                              void* d_out, int out_size, void* d_ws, size_t ws_size,
                              hipStream_t stream) {
    const float* z   = (const float*)d_in[0];
    const float* emb = (const float*)d_in[1];
    float* ee  = (float*)d_ws;
    float* out = (float*)d_out;
    hipLaunchKernelGGL(ee_precompute, dim3(2), dim3(256), 0, stream, emb, ee);
    hipLaunchKernelGGL(vq_nearest, dim3(N_ROWS / RPB), dim3(256), 0, stream,
                       z, emb, ee, out);
}